// Round 15
// baseline (369.100 us; speedup 1.0000x reference)
//
#include <hip/hip_runtime.h>
#include <hip/hip_bf16.h>

// Sizes (fixed by the reference)
#define MMH 256      // M == H == F == 256
#define TT 4
#define NSEMN 40
#define HM 65536     // H*M

using short8 = __attribute__((ext_vector_type(8))) short;
using f32x4  = __attribute__((ext_vector_type(4))) float;

__device__ __forceinline__ unsigned short f2bf(float x) {
  union { float f; unsigned int u; } v; v.f = x;
  unsigned int r = v.u + 0x7fffu + ((v.u >> 16) & 1u);   // RNE
  return (unsigned short)(r >> 16);
}

// ---------------------------------------------------------------------------
// 1) pf = relu(parent @ W_parent + b_parent) -> cat[m*768 + h]  (cf0 slice)
__global__ __launch_bounds__(256) void k_parent(
    const float* __restrict__ pf, const float* __restrict__ Wp,
    const float* __restrict__ bp, float* __restrict__ cat) {
  int j = blockIdx.x * 256 + threadIdx.x;   // 0..65535
  float acc = bp[j];
  #pragma unroll 8
  for (int f = 0; f < MMH; ++f) acc += pf[f] * Wp[(size_t)f * HM + j];
  int m = j >> 8, h = j & 255;
  cat[m * 768 + h] = fmaxf(acc, 0.0f);
}

// ---------------------------------------------------------------------------
// 2) child_exists logits (exact f32) + flags init.  One wave per row m.
__global__ __launch_bounds__(64) void k_cel(
    const float* __restrict__ cat, const float* __restrict__ Wex,
    const float* __restrict__ bex, float* __restrict__ cel,
    float* __restrict__ out_ex, int* __restrict__ flags) {
  int m = blockIdx.x, l = threadIdx.x;
  float s = 0.f;
  for (int h = l; h < MMH; h += 64) s += cat[m * 768 + h] * Wex[h];
  #pragma unroll
  for (int off = 32; off > 0; off >>= 1) s += __shfl_down(s, off);
  if (l == 0) { float v = s + bex[0]; cel[m] = v; out_ex[m] = v; }
  if (m == 0 && l == 0) flags[0] = 0;
}

// ---------------------------------------------------------------------------
// Small f32 GEMM, up-to-4 outputs via gridDim.z (all share A).
__global__ __launch_bounds__(256) void k_gemm16(
    const float* __restrict__ A, int lda,
    const float* __restrict__ B0, const float* __restrict__ B1,
    const float* __restrict__ B2, const float* __restrict__ B3, int ldb,
    const float* __restrict__ bias,
    float* __restrict__ C0, float* __restrict__ C1,
    float* __restrict__ C2, float* __restrict__ C3, int ldc,
    int N2, int K2, int relu) {
  int z = blockIdx.z;
  const float* B = (z == 0) ? B0 : (z == 1) ? B1 : (z == 2) ? B2 : B3;
  float*       C = (z == 0) ? C0 : (z == 1) ? C1 : (z == 2) ? C2 : C3;
  __shared__ float As[16][17], Bs[16][17];
  int tx = threadIdx.x, ty = threadIdx.y;
  int row = blockIdx.y * 16 + ty, col = blockIdx.x * 16 + tx;
  float acc = 0.f;
  for (int k0 = 0; k0 < K2; k0 += 16) {
    As[ty][tx] = A[row * lda + k0 + tx];
    Bs[ty][tx] = (col < N2) ? B[(k0 + ty) * ldb + col] : 0.f;
    __syncthreads();
    #pragma unroll
    for (int kk = 0; kk < 16; ++kk) acc += As[ty][kk] * Bs[kk][tx];
    __syncthreads();
  }
  if (col < N2) {
    if (bias) acc += bias[col];
    if (relu) acc = fmaxf(acc, 0.f);
    C[row * ldc + col] = acc;
  }
}

// ---------------------------------------------------------------------------
// 2.5) Prep: We (f32 [h][k]) -> WeTb bf16 tiled [(h/32)][k][h%32] per iter,
//      plus Wee transposed to float4-per-h table.
__global__ __launch_bounds__(256) void k_tr(
    const float* __restrict__ Wne, const float* __restrict__ Wee,
    unsigned short* __restrict__ WeTb, float* __restrict__ Wee4g) {
  int i = blockIdx.z;
  const float* We = Wne + (size_t)(i * 772 + 512) * 256;
  unsigned short* out = WeTb + i * 65536;
  __shared__ float t[32][33];             // t[h_local][k_local]
  int tx = threadIdx.x, ty = threadIdx.y; // block (32,8)
  int h0 = blockIdx.y * 32, k0 = blockIdx.x * 32;
  #pragma unroll
  for (int j = 0; j < 4; ++j)
    t[ty + j * 8][tx] = We[(size_t)(h0 + ty + j * 8) * 256 + k0 + tx];
  __syncthreads();
  #pragma unroll
  for (int j = 0; j < 4; ++j) {
    int kl = ty + j * 8;
    out[((h0 >> 5) * 256 + k0 + kl) * 32 + tx] = f2bf(t[tx][kl]);
  }
  if (blockIdx.x == 0 && blockIdx.y == 0 && i == 0) {
    int t2 = ty * 32 + tx;
    float4 w;
    w.x = Wee[t2]; w.y = Wee[256 + t2]; w.z = Wee[512 + t2]; w.w = Wee[768 + t2];
    ((float4*)Wee4g)[t2] = w;
  }
}

// ---------------------------------------------------------------------------
// 3) edge_exists_logits (exact f32, thread-per-pair) + has_edge flag
//    + (optional) materialize EL bf16 [pair][h] when workspace allows.
#define XP 260
__global__ __launch_bounds__(256) void k_edge(
    const float* __restrict__ Xi, const float* __restrict__ Xj,
    const float* __restrict__ bel, const float* __restrict__ Wee4g,
    const float* __restrict__ bee, const float* __restrict__ cel,
    float* __restrict__ out_eel, int* __restrict__ flags,
    unsigned short* __restrict__ ELmat) {
  __shared__ float XiS[16 * XP], XjS[16 * XP];
  __shared__ int anyEdge;
  int tid = threadIdx.x;
  int m0 = (blockIdx.x >> 4) * 16, n0 = (blockIdx.x & 15) * 16;
  if (tid == 0) anyEdge = 0;
  #pragma unroll
  for (int j = 0; j < 4; ++j) {
    int c = tid + 256 * j;                 // 1024 chunks of 16B
    int row = c >> 6, c4 = (c & 63) * 4;
    float4 v = *(const float4*)(Xi + (m0 + row) * 256 + c4);
    float4 b = *(const float4*)(bel + c4);
    v.x += b.x; v.y += b.y; v.z += b.z; v.w += b.w;   // fold bel into Xi tile
    *(float4*)&XiS[row * XP + c4] = v;
    *(float4*)&XjS[row * XP + c4] = *(const float4*)(Xj + (n0 + row) * 256 + c4);
  }
  __syncthreads();
  int tm = tid >> 4, tn = tid & 15;
  int m = m0 + tm, n = n0 + tn;
  unsigned short* elp = ELmat ? ELmat + (size_t)(m * 256 + n) * 256 : nullptr;
  const float* xr = &XiS[tm * XP];
  const float* yr = &XjS[tn * XP];
  float4 s = {0.f, 0.f, 0.f, 0.f};
  for (int h = 0; h < 256; h += 8) {
    float4 a0 = *(const float4*)&xr[h], a1 = *(const float4*)&xr[h + 4];
    float4 b0 = *(const float4*)&yr[h], b1 = *(const float4*)&yr[h + 4];
    float e[8];
    e[0] = fmaxf(a0.x + b0.x, 0.f); e[1] = fmaxf(a0.y + b0.y, 0.f);
    e[2] = fmaxf(a0.z + b0.z, 0.f); e[3] = fmaxf(a0.w + b0.w, 0.f);
    e[4] = fmaxf(a1.x + b1.x, 0.f); e[5] = fmaxf(a1.y + b1.y, 0.f);
    e[6] = fmaxf(a1.z + b1.z, 0.f); e[7] = fmaxf(a1.w + b1.w, 0.f);
    if (elp) {
      short8 vv;
      #pragma unroll
      for (int q = 0; q < 8; ++q) vv[q] = (short)f2bf(e[q]);
      *(short8*)&elp[h] = vv;
    }
    #pragma unroll
    for (int q = 0; q < 8; ++q) {
      float4 w = ((const float4*)Wee4g)[h + q];   // uniform -> scalar load
      s.x += e[q] * w.x; s.y += e[q] * w.y;
      s.z += e[q] * w.z; s.w += e[q] * w.w;
    }
  }
  s.x += bee[0]; s.y += bee[1]; s.z += bee[2]; s.w += bee[3];
  ((float4*)out_eel)[m * 256 + n] = s;
  bool edge = (cel[m] > 0.f) && (cel[n] > 0.f) &&
              (s.x > 0.f || s.y > 0.f || s.z > 0.f || s.w > 0.f);
  if (__ballot(edge) != 0ull && (tid & 63) == 0) atomicOr(&anyEdge, 1);
  __syncthreads();
  if (tid == 0 && anyEdge) atomicOr(flags, 1);
}

// ---------------------------------------------------------------------------
__global__ __launch_bounds__(256) void k_zero(float* __restrict__ p) {
  p[blockIdx.x * 256 + threadIdx.x] = 0.f;
}

// ---------------------------------------------------------------------------
// Shared epilogue for both k_iter variants.
__device__ __forceinline__ void iter_epilogue(
    f32x4 (&acc)[4][4], int m0, int n0, int w, int lane,
    const float* __restrict__ Ai, const float* __restrict__ Bj,
    const float* __restrict__ Wt, const float* __restrict__ bne,
    const float* __restrict__ eel, const float* __restrict__ cel,
    float* __restrict__ newcf) {
  int col = lane & 15, grp = lane >> 4;
  #pragma unroll
  for (int rt = 0; rt < 4; ++rt) {
    int m = m0 + rt;
    bool nem = cel[m] > 0.f;
    float4 e4[4]; bool nen[4];
    #pragma unroll
    for (int r = 0; r < 4; ++r) {
      int n = n0 + grp * 4 + r;
      e4[r] = ((const float4*)eel)[m * 256 + n];
      nen[r] = cel[n] > 0.f;
    }
    #pragma unroll
    for (int ct = 0; ct < 4; ++ct) {
      int k = w * 64 + ct * 16 + col;
      float basek = Ai[m * MMH + k] + bne[k];
      float wt0 = Wt[0 * MMH + k], wt1 = Wt[1 * MMH + k];
      float wt2 = Wt[2 * MMH + k], wt3 = Wt[3 * MMH + k];
      float vmax = 0.f;
      #pragma unroll
      for (int r = 0; r < 4; ++r) {
        int n = n0 + grp * 4 + r;
        float base = acc[rt][ct][r] + basek + Bj[n * MMH + k];
        if (nem && nen[r]) {
          if (e4[r].x > 0.f) vmax = fmaxf(vmax, base + e4[r].x * wt0);
          if (e4[r].y > 0.f) vmax = fmaxf(vmax, base + e4[r].y * wt1);
          if (e4[r].z > 0.f) vmax = fmaxf(vmax, base + e4[r].z * wt2);
          if (e4[r].w > 0.f) vmax = fmaxf(vmax, base + e4[r].w * wt3);
        }
      }
      vmax = fmaxf(vmax, __shfl_xor(vmax, 16));
      vmax = fmaxf(vmax, __shfl_xor(vmax, 32));
      if (grp == 0 && vmax > 0.f)
        atomicMax((unsigned int*)&newcf[m * MMH + k], __float_as_uint(vmax));
    }
  }
}

// ---------------------------------------------------------------------------
// 4a) k_iter FAST: zero LDS / zero barriers; A-frags from ELmat [pair][h],
//     B-frags from WeTb [(h/32)][k][h%32]. Bit-identical fragments to 4b.
__global__ __launch_bounds__(256) void k_iter_fast(
    const unsigned short* __restrict__ ELmat,
    const unsigned short* __restrict__ WeTb,
    const float* __restrict__ Ai, const float* __restrict__ Bj,
    const float* __restrict__ Wt, const float* __restrict__ bne,
    const float* __restrict__ eel, const float* __restrict__ cel,
    float* __restrict__ newcf) {
  int tid = threadIdx.x;
  int w = tid >> 6, lane = tid & 63;
  int m0 = (blockIdx.x >> 4) * 4, n0 = (blockIdx.x & 15) * 16;
  int kl = lane & 15, colh = (lane >> 4) * 8;
  f32x4 acc[4][4] = {};
  const unsigned short* elbase = ELmat + ((size_t)(m0 * 256 + n0 + kl)) * 256 + colh;
  const unsigned short* webase = WeTb + (size_t)(w * 64 + kl) * 32 + colh;
  for (int s = 0; s < 8; ++s) {
    int h0 = s * 32;
    short8 af[4], bf[4];
    #pragma unroll
    for (int rt = 0; rt < 4; ++rt)
      af[rt] = *(const short8*)(elbase + (size_t)rt * 65536 + h0);
    #pragma unroll
    for (int ct = 0; ct < 4; ++ct)
      bf[ct] = *(const short8*)(webase + (size_t)(s * 256 + ct * 16) * 32);
    #pragma unroll
    for (int rt = 0; rt < 4; ++rt)
      #pragma unroll
      for (int ct = 0; ct < 4; ++ct)
        acc[rt][ct] = __builtin_amdgcn_mfma_f32_16x16x32_bf16(af[rt], bf[ct], acc[rt][ct], 0, 0, 0);
  }
  iter_epilogue(acc, m0, n0, w, lane, Ai, Bj, Wt, bne, eel, cel, newcf);
}

// ---------------------------------------------------------------------------
// 4b) k_iter LDS fallback (round-9 proven, ~2.7 MB workspace total).
#define ELP 56
__global__ __launch_bounds__(256) void k_iter_lds(
    const float* __restrict__ Xi, const float* __restrict__ Xj,
    const float* __restrict__ bel, const unsigned short* __restrict__ WeTb,
    const float* __restrict__ Ai, const float* __restrict__ Bj,
    const float* __restrict__ Wt, const float* __restrict__ bne,
    const float* __restrict__ eel, const float* __restrict__ cel,
    float* __restrict__ newcf) {
  __shared__ unsigned short ELs[64 * ELP];
  __shared__ unsigned short WesT[256 * ELP];
  int tid = threadIdx.x;
  int w = tid >> 6, lane = tid & 63;
  int m0 = (blockIdx.x >> 4) * 4, n0 = (blockIdx.x & 15) * 16;
  f32x4 acc[4][4] = {};
  for (int h0 = 0; h0 < MMH; h0 += 32) {
    {
      int row = tid & 63, g = tid >> 6;
      int mI = m0 + (row >> 4), nI = n0 + (row & 15);
      const float4* xip = (const float4*)(Xi + mI * MMH + h0 + g * 8);
      const float4* xjp = (const float4*)(Xj + nI * MMH + h0 + g * 8);
      const float4* bp  = (const float4*)(bel + h0 + g * 8);
      float4 x0 = xip[0], x1 = xip[1];
      float4 y0 = xjp[0], y1 = xjp[1];
      float4 c0 = bp[0],  c1 = bp[1];
      short8 v;
      v[0] = (short)f2bf(fmaxf(x0.x + y0.x + c0.x, 0.f));
      v[1] = (short)f2bf(fmaxf(x0.y + y0.y + c0.y, 0.f));
      v[2] = (short)f2bf(fmaxf(x0.z + y0.z + c0.z, 0.f));
      v[3] = (short)f2bf(fmaxf(x0.w + y0.w + c0.w, 0.f));
      v[4] = (short)f2bf(fmaxf(x1.x + y1.x + c1.x, 0.f));
      v[5] = (short)f2bf(fmaxf(x1.y + y1.y + c1.y, 0.f));
      v[6] = (short)f2bf(fmaxf(x1.z + y1.z + c1.z, 0.f));
      v[7] = (short)f2bf(fmaxf(x1.w + y1.w + c1.w, 0.f));
      *(short8*)&ELs[row * ELP + g * 8] = v;
    }
    {
      const unsigned short* WeT = WeTb + (h0 >> 5) * 8192;
      #pragma unroll
      for (int j = 0; j < 4; ++j) {
        int g = tid + 256 * j;
        short8 v = *(const short8*)(WeT + g * 8);
        *(short8*)&WesT[(g >> 2) * ELP + (g & 3) * 8] = v;
      }
    }
    __syncthreads();
    short8 af[4], bf[4];
    #pragma unroll
    for (int rt = 0; rt < 4; ++rt)
      af[rt] = *(const short8*)&ELs[(rt * 16 + (lane & 15)) * ELP + (lane >> 4) * 8];
    #pragma unroll
    for (int ct = 0; ct < 4; ++ct)
      bf[ct] = *(const short8*)&WesT[(w * 64 + ct * 16 + (lane & 15)) * ELP + (lane >> 4) * 8];
    #pragma unroll
    for (int rt = 0; rt < 4; ++rt)
      #pragma unroll
      for (int ct = 0; ct < 4; ++ct)
        acc[rt][ct] = __builtin_amdgcn_mfma_f32_16x16x32_bf16(af[rt], bf[ct], acc[rt][ct], 0, 0, 0);
    __syncthreads();
  }
  iter_epilogue(acc, m0, n0, w, lane, Ai, Bj, Wt, bne, eel, cel, newcf);
}

// ---------------------------------------------------------------------------
// 5) cf_{i+1} = has_edge ? newcf : cf_i ; also re-zero newcf for next iter.
__global__ __launch_bounds__(256) void k_select(
    const int* __restrict__ flags, float* __restrict__ newcf,
    float* __restrict__ cat, int iter) {
  int idx = blockIdx.x * 256 + threadIdx.x;
  int m = idx >> 8, k = idx & 255;
  float prev = cat[m * 768 + iter * 256 + k];
  float v = flags[0] ? newcf[idx] : prev;
  cat[m * 768 + (iter + 1) * 256 + k] = v;
  newcf[idx] = 0.f;
}

// ---------------------------------------------------------------------------
extern "C" void kernel_launch(void* const* d_in, const int* in_sizes, int n_in,
                              void* d_out, int out_size, void* d_ws, size_t ws_size,
                              hipStream_t stream) {
  const float* pf   = (const float*)d_in[0];
  const float* Wp   = (const float*)d_in[1];
  const float* bp   = (const float*)d_in[2];
  const float* Wex  = (const float*)d_in[3];
  const float* bex  = (const float*)d_in[4];
  const float* Wel  = (const float*)d_in[5];
  const float* bel  = (const float*)d_in[6];
  const float* Wee  = (const float*)d_in[7];
  const float* bee  = (const float*)d_in[8];
  const float* Wne  = (const float*)d_in[9];
  const float* bne  = (const float*)d_in[10];
  const float* Wch  = (const float*)d_in[11];
  const float* bch  = (const float*)d_in[12];
  const float* Wsem = (const float*)d_in[13];
  const float* bsem = (const float*)d_in[14];
  const float* Wch2 = (const float*)d_in[15];
  const float* bch2 = (const float*)d_in[16];
  float* out = (float*)d_out;
  float* ws  = (float*)d_ws;

  // workspace layout (floats)
  float* cat    = ws;               // 256 x 768 (cf0|cf1|cf2)
  float* Xi     = ws + 196608;
  float* Xj     = Xi + 65536;
  float* Ai     = Xj + 65536;
  float* Bj     = Ai + 65536;
  float* newcf  = Bj + 65536;
  float* hidden = newcf + 65536;
  float* cel    = hidden + 65536;   // 256
  int*   flags  = (int*)(cel + 256);
  float* Wee4g  = cel + 512;        // 256 x 4
  unsigned short* WeTb  = (unsigned short*)(Wee4g + 1024);  // 2 x 65536 bf16
  unsigned short* ELmat = WeTb + 131072;                    // 65536x256 bf16 (33.5 MB)
  size_t need = (size_t)((char*)(ELmat + (size_t)65536 * 256) - (char*)ws);
  bool fast = ws_size >= need;     // constant across calls -> capture-safe

  float* out_cf  = out;             // (1,256,256)
  float* out_sem = out + 65536;     // (1,256,40)
  float* out_ex  = out + 75776;     // (1,256,1)
  float* out_eel = out + 76032;     // (1,256,256,4)

  const float* Wi0 = Wne + (size_t)(0 * 772 + 0)   * 256;
  const float* Wj0 = Wne + (size_t)(0 * 772 + 256) * 256;
  const float* Wi1 = Wne + (size_t)(1 * 772 + 0)   * 256;
  const float* Wj1 = Wne + (size_t)(1 * 772 + 256) * 256;

  dim3 b16(16, 16);
  k_parent<<<256, 256, 0, stream>>>(pf, Wp, bp, cat);
  k_cel<<<256, 64, 0, stream>>>(cat, Wex, bex, cel, out_ex, flags);
  k_tr<<<dim3(8, 8, 2), dim3(32, 8), 0, stream>>>(Wne, Wee, WeTb, Wee4g);
  k_zero<<<256, 256, 0, stream>>>(newcf);
  // Xi, Xj, A0, B0 all share A=cat (lda=768): one z=4 launch.
  k_gemm16<<<dim3(16, 16, 4), b16, 0, stream>>>(cat, 768,
      Wel, Wel + 65536, Wi0, Wj0, 256, nullptr,
      Xi, Xj, Ai, Bj, 256, 256, 256, 0);
  k_edge<<<256, 256, 0, stream>>>(Xi, Xj, bel, Wee4g, bee, cel, out_eel, flags,
                                  fast ? ELmat : nullptr);
  for (int i = 0; i < 2; ++i) {
    const float* Wt  = Wne + (size_t)(i * 772 + 768) * 256;
    const float* bnei = bne + i * 256;
    if (i == 1) {
      k_gemm16<<<dim3(16, 16, 2), b16, 0, stream>>>(cat + 256, 768,
          Wi1, Wj1, nullptr, nullptr, 256, nullptr,
          Ai, Bj, nullptr, nullptr, 256, 256, 256, 0);
    }
    if (fast)
      k_iter_fast<<<1024, 256, 0, stream>>>(ELmat, WeTb + i * 65536,
                                            Ai, Bj, Wt, bnei, out_eel, cel, newcf);
    else
      k_iter_lds<<<1024, 256, 0, stream>>>(Xi, Xj, bel, WeTb + i * 65536,
                                           Ai, Bj, Wt, bnei, out_eel, cel, newcf);
    k_select<<<256, 256, 0, stream>>>(flags, newcf, cat, i);
  }
  k_gemm16<<<dim3(16, 16, 1), b16, 0, stream>>>(cat, 768,
      Wch, nullptr, nullptr, nullptr, 256, bch,
      hidden, nullptr, nullptr, nullptr, 256, 256, 768, 1);
  k_gemm16<<<dim3(3, 16, 1), b16, 0, stream>>>(hidden, 256,
      Wsem, nullptr, nullptr, nullptr, 40, bsem,
      out_sem, nullptr, nullptr, nullptr, 40, NSEMN, 256, 0);
  k_gemm16<<<dim3(16, 16, 1), b16, 0, stream>>>(hidden, 256,
      Wch2, nullptr, nullptr, nullptr, 256, bch2,
      out_cf, nullptr, nullptr, nullptr, 256, 256, 256, 1);
}